// Round 2
// baseline (16135.036 us; speedup 1.0000x reference)
//
#include <hip/hip_runtime.h>

#define NROWS 65536
#define DD 512
#define MSZ (DD * DD)          // 262144 floats = 1 MB
#define NS_ITERS 7
#define BARY_ITERS 16
#define CSPLIT 16              // covsyrk split-K
#define CCHUNK (NROWS / CSPLIT)  // 4096

// ---------------- column means ----------------
__global__ __launch_bounds__(512) void colsum_kernel(const float* __restrict__ X,
                                                     const float* __restrict__ S,
                                                     float* __restrict__ sums) {
    const float* src = (blockIdx.y == 0) ? X : S;
    float* dst = sums + blockIdx.y * DD;
    int col = threadIdx.x;
    long base = (long)blockIdx.x * 256 * DD;
    float acc = 0.f;
    #pragma unroll 8
    for (int r = 0; r < 256; ++r)
        acc += src[base + (long)r * DD + col];
    atomicAdd(dst + col, acc);
}

__global__ __launch_bounds__(512) void finalize_mean_kernel(float* __restrict__ ws) {
    int t = threadIdx.x;
    const float inv_n = 1.f / (float)NROWS;
    float mc = ws[t] * inv_n;
    float ms = ws[DD + t] * inv_n;
    ws[t] = mc;
    ws[DD + t] = ms;
    ws[2 * DD + t] = 0.5f * (mc + ms);   // mu_bary
}

// ---------------- covariance: G = X^T X, 128x128 upper tiles, split-K atomics ----------------
// grid: x = 16 (4x4 tiles of 128), y = CSPLIT, z = 2 (mat); 256 threads, 8x8 micro.
__global__ __launch_bounds__(256) void covsyrk2_kernel(const float* __restrict__ X,
                                                       const float* __restrict__ S,
                                                       float* __restrict__ G) {
    int ta = blockIdx.x >> 2, tb = blockIdx.x & 3;
    if (ta > tb) return;                       // symmetry: upper 128-tiles only
    int a0 = ta << 7, b0 = tb << 7;
    const float* src = (blockIdx.z == 0) ? X : S;
    float* g = G + (long long)blockIdx.z * MSZ;
    long kbase = (long)blockIdx.y * CCHUNK;
    __shared__ float As[32][140];
    __shared__ float Bs[32][140];
    int t = threadIdx.x;
    int kr = t >> 5;              // 0..7
    int c4 = (t & 31) << 2;       // 0..124
    int sc = c4 + ((c4 >> 5) << 2);   // quad swizzle
    int iy = t >> 4, ix = t & 15;
    int aoff = (iy << 3) + ((iy >> 2) << 2);
    int boff = (ix << 3) + ((ix >> 2) << 2);
    float acc[8][8] = {};
    float4 pa[4], pb[4];
    #pragma unroll
    for (int p = 0; p < 4; ++p) {
        long row = (kbase + kr + p * 8) * DD;
        pa[p] = *(const float4*)(src + row + a0 + c4);
        pb[p] = *(const float4*)(src + row + b0 + c4);
    }
    for (int kb = 0; kb < CCHUNK; kb += 32) {
        __syncthreads();
        #pragma unroll
        for (int p = 0; p < 4; ++p) {
            *(float4*)&As[kr + p * 8][sc] = pa[p];
            *(float4*)&Bs[kr + p * 8][sc] = pb[p];
        }
        __syncthreads();
        if (kb + 32 < CCHUNK) {
            #pragma unroll
            for (int p = 0; p < 4; ++p) {
                long row = (kbase + kb + 32 + kr + p * 8) * DD;
                pa[p] = *(const float4*)(src + row + a0 + c4);
                pb[p] = *(const float4*)(src + row + b0 + c4);
            }
        }
        #pragma unroll 4
        for (int kk = 0; kk < 32; ++kk) {
            float a[8], bf[8];
            *(float4*)&a[0] = *(const float4*)&As[kk][aoff];
            *(float4*)&a[4] = *(const float4*)&As[kk][aoff + 4];
            *(float4*)&bf[0] = *(const float4*)&Bs[kk][boff];
            *(float4*)&bf[4] = *(const float4*)&Bs[kk][boff + 4];
            #pragma unroll
            for (int i = 0; i < 8; ++i)
                #pragma unroll
                for (int j = 0; j < 8; ++j)
                    acc[i][j] += a[i] * bf[j];
        }
    }
    #pragma unroll
    for (int i = 0; i < 8; ++i)
        #pragma unroll
        for (int j = 0; j < 8; ++j)
            atomicAdd(&g[(long)(a0 + (iy << 3) + i) * DD + b0 + (ix << 3) + j], acc[i][j]);
}

// cov = (G - n m m^T) / (n-1); reads upper 128-tile (mirror), writes full matrix
__global__ __launch_bounds__(512) void covfix_kernel(const float* __restrict__ Gt,
                                                     float* __restrict__ C,
                                                     const float* __restrict__ means) {
    int m = blockIdx.y, i = blockIdx.x, j = threadIdx.x;
    const float* mu = means + m * DD;
    const float* g = Gt + (long)m * MSZ;
    int ii = i, jj = j;
    if ((ii >> 7) > (jj >> 7)) { int tmp = ii; ii = jj; jj = tmp; }
    float v = g[(long)ii * DD + jj];
    C[(long)m * MSZ + (long)i * DD + j] =
        (v - (float)NROWS * mu[i] * mu[j]) * (1.f / (float)(NROWS - 1));
}

// ---------------- Newton-Schulz support ----------------
// slots per context: [c, 1/c, sqrt(c), 1/sqrt(c)]
__global__ __launch_bounds__(512) void trace_kernel(const float* __restrict__ Abase, long long stride,
                                                    float* __restrict__ slotbase, long long slotstride) {
    __shared__ float red[512];
    const float* A = Abase + (long long)blockIdx.x * stride;
    int t = threadIdx.x;
    red[t] = A[(long)t * DD + t];
    __syncthreads();
    for (int s = 256; s > 0; s >>= 1) {
        if (t < s) red[t] += red[t + s];
        __syncthreads();
    }
    if (t == 0) {
        float c = 2.5f * red[0] / (float)DD;
        float* sl = slotbase + (long long)blockIdx.x * slotstride;
        sl[0] = c;
        sl[1] = 1.f / c;
        sl[2] = sqrtf(c);
        sl[3] = 1.f / sqrtf(c);
    }
}

__global__ __launch_bounds__(512) void nsinit_kernel(const float* __restrict__ Abase, long long sA,
                                                     float* __restrict__ Ybase, long long sY,
                                                     float* __restrict__ Zbase, long long sZ,
                                                     const float* __restrict__ slotbase, long long slotstride) {
    int z = blockIdx.y;
    const float* A = Abase + (long long)z * sA;
    float* Y = Ybase + (long long)z * sY;
    float* Z = Zbase + (long long)z * sZ;
    float invc = slotbase[(long long)z * slotstride + 1];
    int idx = blockIdx.x * 512 + threadIdx.x;
    int row = idx >> 9, col = idx & 511;
    Y[idx] = A[idx] * invc;
    Z[idx] = (row == col) ? 1.f : 0.f;
}

// ---------------- FMA-bound 512x512 matmul: partial sums to pool (in d_out) ----------------
// grid: x = 16 tiles (4x4 of 128x128), y = ksplit, z = batch; 256 threads, 8x8 micro.
__global__ __launch_bounds__(256) void mmk(const float* __restrict__ A, long long sA,
                                           const float* __restrict__ B, long long sB,
                                           float* __restrict__ pool) {
    int ks = gridDim.y;
    int b = blockIdx.z, s = blockIdx.y;
    int i0 = (blockIdx.x >> 2) << 7;
    int j0 = (blockIdx.x & 3) << 7;
    int Ks = DD / ks;
    int kbase = s * Ks;
    const float* Ab = A + (long long)b * sA;
    const float* Bb = B + (long long)b * sB;
    __shared__ float As[32][132];   // As[k][i] (A transposed)
    __shared__ float Bs[32][140];   // quad-swizzled columns
    int t = threadIdx.x;
    int iy = t >> 4, ix = t & 15;
    int ldr = t >> 3;               // 0..31
    int ldc = (t & 7) << 2;         // 0,4,...,28
    int boff = (ix << 3) + ((ix >> 2) << 2);
    float acc[8][8] = {};
    float4 pa[4], pb[4];
    #pragma unroll
    for (int p = 0; p < 4; ++p) {
        pa[p] = *(const float4*)(Ab + (long)(i0 + ldr + p * 32) * DD + kbase + ldc);
        pb[p] = *(const float4*)(Bb + (long)(kbase + ldr) * DD + j0 + ldc + p * 32);
    }
    for (int kb = 0; kb < Ks; kb += 32) {
        __syncthreads();
        #pragma unroll
        for (int p = 0; p < 4; ++p) {
            int r = ldr + p * 32;
            As[ldc + 0][r] = pa[p].x; As[ldc + 1][r] = pa[p].y;
            As[ldc + 2][r] = pa[p].z; As[ldc + 3][r] = pa[p].w;
            int q = (ldc + p * 32) >> 2;
            *(float4*)&Bs[ldr][(q << 2) + ((q >> 3) << 2)] = pb[p];
        }
        __syncthreads();
        if (kb + 32 < Ks) {
            int k0 = kbase + kb + 32;
            #pragma unroll
            for (int p = 0; p < 4; ++p) {
                pa[p] = *(const float4*)(Ab + (long)(i0 + ldr + p * 32) * DD + k0 + ldc);
                pb[p] = *(const float4*)(Bb + (long)(k0 + ldr) * DD + j0 + ldc + p * 32);
            }
        }
        #pragma unroll 4
        for (int kk = 0; kk < 32; ++kk) {
            float a[8], bf[8];
            *(float4*)&a[0] = *(const float4*)&As[kk][iy << 3];
            *(float4*)&a[4] = *(const float4*)&As[kk][(iy << 3) + 4];
            *(float4*)&bf[0] = *(const float4*)&Bs[kk][boff];
            *(float4*)&bf[4] = *(const float4*)&Bs[kk][boff + 4];
            #pragma unroll
            for (int i = 0; i < 8; ++i)
                #pragma unroll
                for (int j = 0; j < 8; ++j)
                    acc[i][j] += a[i] * bf[j];
        }
    }
    float* P = pool + (long long)(b * ks + s) * MSZ;
    #pragma unroll
    for (int i = 0; i < 8; ++i) {
        long off = (long)(i0 + (iy << 3) + i) * DD + j0 + (ix << 3);
        *(float4*)(P + off) = *(float4*)&acc[i][0];
        *(float4*)(P + off + 4) = *(float4*)&acc[i][4];
    }
}

// C_b = alpha*(aptr?*aptr:1)*sum_s pool[b*ks+s] + beta*D_b, split D/C chains (in-place safe).
__global__ __launch_bounds__(256) void reduce_kernel(const float* __restrict__ pool, int ks,
        const float* __restrict__ D1, long long sD1,
        const float* __restrict__ D2, long long sD2, int dsplit,
        float* __restrict__ C1, long long sC1,
        float* __restrict__ C2, long long sC2, int csplit,
        float alpha, float beta, const float* __restrict__ aptr) {
    int b = blockIdx.y;
    long idx = (long)blockIdx.x * 1024 + (threadIdx.x << 2);
    const float* P = pool + (long long)b * ks * MSZ + idx;
    float4 acc = *(const float4*)P;
    for (int k = 1; k < ks; ++k) {
        float4 v = *(const float4*)(P + (long long)k * MSZ);
        acc.x += v.x; acc.y += v.y; acc.z += v.z; acc.w += v.w;
    }
    float aeff = alpha * (aptr ? *aptr : 1.f);
    acc.x *= aeff; acc.y *= aeff; acc.z *= aeff; acc.w *= aeff;
    if (beta != 0.f) {
        const float* D = (b < dsplit) ? D1 + (long long)b * sD1
                                      : D2 + (long long)(b - dsplit) * sD2;
        float4 d = *(const float4*)(D + idx);
        acc.x += beta * d.x; acc.y += beta * d.y;
        acc.z += beta * d.z; acc.w += beta * d.w;
    }
    float* C = (b < csplit) ? C1 + (long long)b * sC1
                            : C2 + (long long)(b - csplit) * sC2;
    *(float4*)(C + idx) = acc;
}

// Q = 0.5*(sqrt(c0)*Y0 + sqrt(c1)*Y1)
__global__ __launch_bounds__(512) void combineQ_kernel(const float* __restrict__ Y0,
                                                       const float* __restrict__ Y1,
                                                       const float* __restrict__ sl1,
                                                       const float* __restrict__ sl2,
                                                       float* __restrict__ Q) {
    int idx = blockIdx.x * 512 + threadIdx.x;
    Q[idx] = 0.5f * (sl1[2] * Y0[idx] + sl2[2] * Y1[idx]);
}

__global__ __launch_bounds__(512) void symmetrize_kernel(const float* __restrict__ V,
                                                         float* __restrict__ Sg) {
    int i = blockIdx.x, j = threadIdx.x;
    Sg[(long)i * DD + j] = 0.5f * (V[(long)i * DD + j] + V[(long)j * DD + i]);
}

// bias_j = mu_b[j] - sum_k mu_c[k]*M[j][k]
__global__ __launch_bounds__(64) void bias_kernel(const float* __restrict__ M,
                                                  const float* __restrict__ means,
                                                  float* __restrict__ bias) {
    int j = blockIdx.x;
    int lane = threadIdx.x;
    const float* mu_c = means;
    const float* mu_b = means + 2 * DD;
    float p = 0.f;
    for (int k = lane; k < DD; k += 64)
        p += mu_c[k] * M[(long)j * DD + k];
    #pragma unroll
    for (int off = 32; off > 0; off >>= 1)
        p += __shfl_down(p, off, 64);
    if (lane == 0) bias[j] = mu_b[j] - p;
}

// out = X @ M^T + bias; 128x128 tiles, 8x8 micro. grid (4 j-tiles, 512 i-tiles).
__global__ __launch_bounds__(256) void outgemm2_kernel(const float* __restrict__ X,
                                                       const float* __restrict__ M,
                                                       const float* __restrict__ bias,
                                                       float* __restrict__ out) {
    int j0 = blockIdx.x << 7;
    int i0 = blockIdx.y << 7;
    __shared__ float As[32][132];   // As[k][i]
    __shared__ float Bs[32][140];   // Bs[k][j], quad-swizzled j
    int t = threadIdx.x;
    int iy = t >> 4, ix = t & 15;
    int ldr = t >> 3;               // 0..31
    int ldc = (t & 7) << 2;         // 0..28 (k within 32-block)
    int boff = (ix << 3) + ((ix >> 2) << 2);
    float acc[8][8] = {};
    float4 pa[4], pb[4];
    #pragma unroll
    for (int p = 0; p < 4; ++p) {
        pa[p] = *(const float4*)(X + (long)(i0 + ldr + p * 32) * DD + ldc);
        pb[p] = *(const float4*)(M + (long)(j0 + ldr + p * 32) * DD + ldc);
    }
    for (int kb = 0; kb < DD; kb += 32) {
        __syncthreads();
        #pragma unroll
        for (int p = 0; p < 4; ++p) {
            int r = ldr + p * 32;
            As[ldc + 0][r] = pa[p].x; As[ldc + 1][r] = pa[p].y;
            As[ldc + 2][r] = pa[p].z; As[ldc + 3][r] = pa[p].w;
            int q = r >> 2;
            int bc = (q << 2) + ((q >> 3) << 2) + (r & 3);
            Bs[ldc + 0][bc] = pb[p].x; Bs[ldc + 1][bc] = pb[p].y;
            Bs[ldc + 2][bc] = pb[p].z; Bs[ldc + 3][bc] = pb[p].w;
        }
        __syncthreads();
        if (kb + 32 < DD) {
            #pragma unroll
            for (int p = 0; p < 4; ++p) {
                pa[p] = *(const float4*)(X + (long)(i0 + ldr + p * 32) * DD + kb + 32 + ldc);
                pb[p] = *(const float4*)(M + (long)(j0 + ldr + p * 32) * DD + kb + 32 + ldc);
            }
        }
        #pragma unroll 4
        for (int kk = 0; kk < 32; ++kk) {
            float a[8], bf[8];
            *(float4*)&a[0] = *(const float4*)&As[kk][iy << 3];
            *(float4*)&a[4] = *(const float4*)&As[kk][(iy << 3) + 4];
            *(float4*)&bf[0] = *(const float4*)&Bs[kk][boff];
            *(float4*)&bf[4] = *(const float4*)&Bs[kk][boff + 4];
            #pragma unroll
            for (int i = 0; i < 8; ++i)
                #pragma unroll
                for (int j = 0; j < 8; ++j)
                    acc[i][j] += a[i] * bf[j];
        }
    }
    float4 bv0 = *(const float4*)(bias + j0 + (ix << 3));
    float4 bv1 = *(const float4*)(bias + j0 + (ix << 3) + 4);
    #pragma unroll
    for (int i = 0; i < 8; ++i) {
        long off = (long)(i0 + (iy << 3) + i) * DD + j0 + (ix << 3);
        float4 v0 = *(float4*)&acc[i][0];
        float4 v1 = *(float4*)&acc[i][4];
        v0.x += bv0.x; v0.y += bv0.y; v0.z += bv0.z; v0.w += bv0.w;
        v1.x += bv1.x; v1.y += bv1.y; v1.z += bv1.z; v1.w += bv1.w;
        *(float4*)(out + off) = v0;
        *(float4*)(out + off + 4) = v1;
    }
}

// ---------------- host orchestration ----------------
extern "C" void kernel_launch(void* const* d_in, const int* in_sizes, int n_in,
                              void* d_out, int out_size, void* d_ws, size_t ws_size,
                              hipStream_t stream) {
    const float* X = (const float*)d_in[0];
    const float* S = (const float*)d_in[1];
    float* out = (float*)d_out;
    float* ws = (float*)d_ws;
    float* pool = out;   // 16 MB partial pool lives in d_out (128 MB); dead until final outgemm

    // ws layout (floats):
    // [0,512)=mean_c [512,1024)=mean_s [1024,1536)=mu_b [1536,2048)=bias
    // [2048..)=scalar slots (slot0@2048; slot1@2056 stride 8)
    // MATS = ws+4096 (15 matrices total, ~15 MB -- under the 24 MB proven footprint):
    //  m0 covc, m1 covs, m2 Sigma
    //  m3 Ysig, m4 Wsig/U, m5 Zsig        (ns_single block, in-place NS)
    //  m6 Q / final M
    //  m7,m8 mid0,mid1 (m7 also V)
    //  m9..m14 batch blk = [Y0,Y1,W0,W1,Z0,Z1] (nb=1 uses m9,m10,m11)
    float* bias  = ws + 1536;
    float* slot0 = ws + 2048;
    float* slot1 = ws + 2056;
    float* MATS  = ws + 4096;
    auto m_ = [&](int i) { return MATS + (long long)i * MSZ; };
    float* covc  = m_(0);
    float* Sigma = m_(2);
    float* Q     = m_(6);
    float* mid   = m_(7);

    hipMemsetAsync(ws, 0, 1024 * sizeof(float), stream);             // mean sums
    hipMemsetAsync(pool, 0, 2ll * MSZ * sizeof(float), stream);      // syrk accumulators

    colsum_kernel<<<dim3(256, 2), 512, 0, stream>>>(X, S, ws);
    finalize_mean_kernel<<<1, 512, 0, stream>>>(ws);
    covsyrk2_kernel<<<dim3(16, CSPLIT, 2), 256, 0, stream>>>(X, S, pool);
    covfix_kernel<<<dim3(512, 2), 512, 0, stream>>>(pool, covc, ws);
    hipMemcpyAsync(Sigma, covc, MSZ * sizeof(float), hipMemcpyDeviceToDevice, stream);

    // split-K matmul: C chain = alpha*(aptr)*A_b@B_b + beta*D chain. ks*batch = 16 slices.
    auto mm = [&](const float* A, long long sA, const float* B, long long sB,
                  const float* D1, long long sD1, const float* D2, long long sD2, int dsplit,
                  float* C1, long long sC1, float* C2, long long sC2, int csplit,
                  float alpha, float beta, const float* aptr, int batch) {
        int ks = 16 / batch;
        mmk<<<dim3(16, ks, batch), 256, 0, stream>>>(A, sA, B, sB, pool);
        reduce_kernel<<<dim3(256, batch), 256, 0, stream>>>(pool, ks, D1, sD1, D2, sD2, dsplit,
                                                            C1, sC1, C2, sC2, csplit,
                                                            alpha, beta, aptr);
    };
    auto mms = [&](const float* A, long long sA, const float* B, long long sB,
                   float* C, long long sC, float alpha, const float* aptr, int batch) {
        mm(A, sA, B, sB, nullptr, 0, nullptr, 0, batch,
           C, sC, nullptr, 0, batch, alpha, 0.f, aptr, batch);
    };

    // in-place coupled Newton-Schulz on nb matrices.
    // blk layout: Y[0..nb) @ base, W @ base+nb*MSZ, Z @ base+2nb*MSZ (stride MSZ).
    // After: sqrt(A) = sqrt(c)*Y, A^{-1/2} = Z/sqrt(c); Y at base, Z at base+2nb*MSZ.
    auto ns = [&](float* base, const float* Ain, long long sAin, int nb, float* slots) {
        float* Y = base;
        float* W = base + (long long)nb * MSZ;
        float* Z = base + 2ll * nb * MSZ;
        trace_kernel<<<nb, 512, 0, stream>>>(Ain, sAin, slots, 8);
        nsinit_kernel<<<dim3(512, nb), 512, 0, stream>>>(Ain, sAin, Y, MSZ, Z, MSZ, slots, 8);
        for (int it = 0; it < NS_ITERS; ++it) {
            mms(Z, MSZ, Y, MSZ, W, MSZ, 1.f, nullptr, nb);           // W_b = Z_b@Y_b
            // batch 2nb, in place: b<nb: Y_b = 1.5Y_b - 0.5*Y_b@W_b
            //                      b>=nb: Z_b = 1.5Z_b - 0.5*W_b@Z_b
            mm(Y, MSZ, W, MSZ,
               Y, MSZ, Z, MSZ, nb,
               Y, MSZ, Z, MSZ, nb,
               -0.5f, 1.5f, nullptr, 2 * nb);
        }
    };

    float* Ysig = m_(3);
    float* Zsig = m_(5);
    float* Yb   = m_(9);

    for (int iter = 0; iter < BARY_ITERS; ++iter) {
        ns(m_(3), Sigma, 0, 1, slot0);                 // Ysig=m3, Zsig=m5
        // P_j = Ysig @ cov_j -> m9,m10 (batch blk area, free here)
        mms(Ysig, 0, covc, MSZ, m_(9), MSZ, 1.f, nullptr, 2);
        // mid_j = c0 * P_j @ Ysig -> m7,m8
        mms(m_(9), MSZ, Ysig, 0, mid, MSZ, 1.f, slot0, 2);
        ns(m_(9), mid, MSZ, 2, slot1);                 // Yb0=m9, Yb1=m10
        // Q = 0.5*(sqrt(c1)*Yb0 + sqrt(c2)*Yb1)
        combineQ_kernel<<<512, 512, 0, stream>>>(m_(9), m_(10), slot1, slot1 + 8, Q);
        mms(Zsig, 0, Q, 0, m_(4), 0, 1.f, nullptr, 1);               // U = Zsig@Q -> m4
        mms(m_(4), 0, Zsig, 0, mid, 0, 1.f, slot0 + 1, 1);           // V = (1/c0)*U@Zsig -> m7
        symmetrize_kernel<<<512, 512, 0, stream>>>(mid, Sigma);
    }

    // final transform: M = covc^{-1/2} (covc^{1/2} Sigma covc^{1/2})^{1/2} covc^{-1/2}
    ns(m_(3), covc, 0, 1, slot0);                      // Ysig=m3, Zsig=m5
    mms(Ysig, 0, Sigma, 0, m_(9), 0, 1.f, nullptr, 1);               // P = Y@Sigma -> m9
    mms(m_(9), 0, Ysig, 0, mid, 0, 1.f, slot0, 1);                   // mid = c0*P@Y -> m7
    ns(m_(9), mid, 0, 1, slot1);                       // Yb=m9 (W=m10, Z=m11)
    mms(Zsig, 0, Yb, 0, m_(4), 0, 1.f, slot1 + 2, 1);                // U = sqrt(c1)*Zsig@Yb -> m4
    mms(m_(4), 0, Zsig, 0, Q, 0, 1.f, slot0 + 1, 1);                 // M = (1/c0)*U@Zsig -> m6
    bias_kernel<<<512, 64, 0, stream>>>(Q, ws, bias);
    outgemm2_kernel<<<dim3(4, 512), 256, 0, stream>>>(X, Q, bias, out);
}